// Round 14
// baseline (58.935 us; speedup 1.0000x reference)
//
#include <hip/hip_runtime.h>

typedef float f32x4 __attribute__((ext_vector_type(4)));
typedef float f32x16 __attribute__((ext_vector_type(16)));
typedef unsigned int u32x4 __attribute__((ext_vector_type(4)));
typedef __bf16 bf16x8 __attribute__((ext_vector_type(8)));
typedef unsigned short ushort_t;

#define NEG2 (-144269.5f)   /* -1e5 * log2(e) */
#define SCLQ (0.18033688f)  /* 0.125 * log2(e) */

constexpr int Ss = 2048, Ee = 1024, Hh = 64;

static __device__ __forceinline__ ushort_t f2bfu(float f) {
  return __builtin_bit_cast(ushort_t, (__bf16)f);
}
static __device__ __forceinline__ f32x4 mfma16(bf16x8 a, bf16x8 b, f32x4 c) {
  return __builtin_amdgcn_mfma_f32_16x16x32_bf16(a, b, c, 0, 0, 0);
}
static __device__ __forceinline__ f32x16 mfma32(bf16x8 a, bf16x8 b, f32x16 c) {
  return __builtin_amdgcn_mfma_f32_32x32x16_bf16(a, b, c, 0, 0, 0);
}
static __device__ __forceinline__ unsigned cvtpk(float a, float b) {
  unsigned r;
  asm("v_cvt_pk_bf16_f32 %0, %1, %2" : "=v"(r) : "v"(a), "v"(b));
  return r;
}
// NOTE: only call with a,b holding DIFFERENT values (R3 bug: identical values
// tie to one phys reg -> in-place self-swap).
static __device__ __forceinline__ void swap32(unsigned& a, unsigned& b) {
  asm("v_permlane32_swap_b32 %0, %1" : "+v"(a), "+v"(b));
}

// ============ Fragment-major layouts (ushort element offsets) ============
// Q/K: F(b,t32,c,hi,lo,j) = ((((b*64+t32)*4+c)*2+hi)*32+lo)*8+j
// V:   G(b,s16,dt,hi,lo,j) = ((((b*128+s16)*2+dt)*2+hi)*32+lo)*8+j

// ---------------- weight transpose + bf16 convert: Wt[m][h][e] ----------------
__global__ __launch_bounds__(256) void k_wtrans(const float* __restrict__ Wq,
                                                const float* __restrict__ Wk,
                                                const float* __restrict__ Wv,
                                                ushort_t* __restrict__ Wt) {
  __shared__ float tile[64][65];
  const float* W = (blockIdx.y == 0) ? Wq : (blockIdx.y == 1 ? Wk : Wv);
  int kt = blockIdx.x, t = threadIdx.x;
  int r = t >> 2, cq = t & 3;
  const float* src = W + (kt * 64 + r) * Hh + cq * 16;
#pragma unroll
  for (int j = 0; j < 16; j += 4) {
    float4 v = *reinterpret_cast<const float4*>(src + j);
    tile[r][cq * 16 + j + 0] = v.x;
    tile[r][cq * 16 + j + 1] = v.y;
    tile[r][cq * 16 + j + 2] = v.z;
    tile[r][cq * 16 + j + 3] = v.w;
  }
  __syncthreads();
  int n = t >> 2, kq = t & 3;
  ushort_t ob[16];
#pragma unroll
  for (int j = 0; j < 16; ++j) ob[j] = f2bfu(tile[kq * 16 + j][n]);
  ushort_t* dst = Wt + ((size_t)blockIdx.y * 64 + n) * Ee + kt * 64 + kq * 16;
  reinterpret_cast<uint4*>(dst)[0] = reinterpret_cast<uint4*>(ob)[0];
  reinterpret_cast<uint4*>(dst)[1] = reinterpret_cast<uint4*>(ob)[1];
}

// ---------------- fused QKV projection: LDS-staged, double-buffered ----------------
// (R6 core, unchanged) — epilogue scatters into fragment-major q/k/v layouts.
__global__ __launch_bounds__(512, 4) void k_proj(const float* __restrict__ hs,
                                                 const float* __restrict__ bq,
                                                 const float* __restrict__ bk,
                                                 const float* __restrict__ bv,
                                                 const ushort_t* __restrict__ Wt,
                                                 const int* __restrict__ am,
                                                 ushort_t* __restrict__ qf_,
                                                 ushort_t* __restrict__ kf_,
                                                 ushort_t* __restrict__ vf_,
                                                 float* __restrict__ pen) {
  __shared__ __align__(16) ushort_t bufA[2][64][72];   // 18 KB
  __shared__ __align__(16) ushort_t bufW[2][192][72];  // 54 KB

  int t = threadIdx.x, w = t >> 6, l = t & 63, g = l >> 4, c = l & 15;
  int wm = w >> 1, wn = w & 1;
  int row0 = blockIdx.x * 64;

  int ar = t >> 3, ach = t & 7;
  const float* agp = hs + (size_t)(row0 + ar) * Ee + ach * 8;
  const ushort_t* wgp = Wt + (size_t)(t >> 3) * Ee + (t & 7) * 8;

  f32x4 acc[6];
#pragma unroll
  for (int nt = 0; nt < 6; ++nt) acc[nt] = f32x4{0.f, 0.f, 0.f, 0.f};

  float4 aR0, aR1;
  u32x4 wR[3];

  auto LOAD = [&](int kk) {
    aR0 = *reinterpret_cast<const float4*>(agp + kk);
    aR1 = *reinterpret_cast<const float4*>(agp + kk + 4);
#pragma unroll
    for (int j = 0; j < 3; ++j)
      wR[j] = *reinterpret_cast<const u32x4*>(wgp + (size_t)j * 64 * Ee + kk);
  };
  auto WRITE = [&](int buf) {
    bf16x8 av;
    av[0] = (__bf16)aR0.x; av[1] = (__bf16)aR0.y; av[2] = (__bf16)aR0.z; av[3] = (__bf16)aR0.w;
    av[4] = (__bf16)aR1.x; av[5] = (__bf16)aR1.y; av[6] = (__bf16)aR1.z; av[7] = (__bf16)aR1.w;
    *reinterpret_cast<bf16x8*>(&bufA[buf][ar][ach * 8]) = av;
#pragma unroll
    for (int j = 0; j < 3; ++j)
      *reinterpret_cast<u32x4*>(&bufW[buf][(t >> 3) + j * 64][(t & 7) * 8]) = wR[j];
  };
  auto COMPUTE = [&](int buf) {
    const ushort_t* Ab = &bufA[buf][wm * 16 + c][0];
    bf16x8 af0 = *reinterpret_cast<const bf16x8*>(Ab + g * 8);
    bf16x8 af1 = *reinterpret_cast<const bf16x8*>(Ab + 32 + g * 8);
#pragma unroll
    for (int nt = 0; nt < 6; ++nt) {
      const ushort_t* Wb = &bufW[buf][wn * 96 + nt * 16 + c][0];
      bf16x8 b0 = *reinterpret_cast<const bf16x8*>(Wb + g * 8);
      bf16x8 b1 = *reinterpret_cast<const bf16x8*>(Wb + 32 + g * 8);
      acc[nt] = mfma16(af0, b0, acc[nt]);
      acc[nt] = mfma16(af1, b1, acc[nt]);
    }
  };

  LOAD(0);
  WRITE(0);
  __syncthreads();

  int cur = 0;
  for (int s = 0; s < 16; ++s) {
    if (s < 15) LOAD((s + 1) * 64);
    COMPUTE(cur);
    if (s < 15) {
      __syncthreads();
      WRITE(cur ^ 1);
      __syncthreads();
      cur ^= 1;
    }
  }

  // epilogue: scatter into fragment-major layouts
#pragma unroll
  for (int nt = 0; nt < 6; ++nt) {
    int T = wn * 6 + nt;
    int m = T >> 2;
    int h = (T & 3) * 16 + c;
    const float* bias = (m == 0) ? bq : ((m == 1) ? bk : bv);
    float bb = bias[h];
    int cc = h >> 4, hh = (h >> 3) & 1, jj = h & 7;      // Q/K frag coords
    int dt = h >> 5, dl = h & 31;                         // V frag coords
#pragma unroll
    for (int i = 0; i < 4; ++i) {
      int row = row0 + wm * 16 + g * 4 + i;
      float val = acc[nt][i] + bb;
      int bi = row >> 11, rl = row & 2047;
      if (m == 0) {
        size_t a = ((((size_t)(bi * 64 + (rl >> 5)) * 4 + cc) * 2 + hh) * 32 + (rl & 31)) * 8 + jj;
        qf_[a] = f2bfu(val * SCLQ);
      } else if (m == 1) {
        size_t a = ((((size_t)(bi * 64 + (rl >> 5)) * 4 + cc) * 2 + hh) * 32 + (rl & 31)) * 8 + jj;
        kf_[a] = f2bfu(val);
      } else {
        int s16 = rl >> 4, vh = (rl >> 3) & 1, vj = rl & 7;
        size_t a = ((((size_t)(bi * 128 + s16) * 2 + dt) * 2 + vh) * 32 + dl) * 8 + vj;
        vf_[a] = f2bfu(val);
      }
    }
  }

  if (t < 64) {
    int grow = row0 + t;
    int bi = grow >> 11, s2 = grow & 2047;
    int mv = am[grow];
    pen[((size_t)bi * 2 + 0) * Ss + s2] = mv ? 0.f : NEG2;
    pen[((size_t)bi * 2 + 1) * Ss + s2] = mv ? NEG2 : 0.f;
  }
}

// ---------------- fused masked flash attention v4: frag-major + K/pen prefetch ----
// grid 1024: b = bid&7 (batch-per-XCD), qt = (bid>>3)&63, kh = bid>>9 (k-split).
// 256 thr / 4 waves; wave w owns keys [kh*1024 + w*256, +256) = 8 tiles of 32.
// Latency plan: K+pen for it+1 issued at top of it (1-deep register prefetch,
// full iteration ~300+ cyc of cover); V for it issued at top of it (PV use is
// ~150 cyc later, after QK+softmax). sched_barrier(0) pins the load cluster —
// hipcc otherwise sinks loads to uses (R5). V deliberately NOT double-buffered
// to stay under the (256,3) ~170-VGPR cap (R12 spill lesson).
__global__ __launch_bounds__(256, 3) void k_attn(const ushort_t* __restrict__ qs,
                                                 const ushort_t* __restrict__ km,
                                                 const ushort_t* __restrict__ vm,
                                                 const int* __restrict__ am,
                                                 const float* __restrict__ pen,
                                                 float* __restrict__ opart,
                                                 float* __restrict__ lpart) {
  __shared__ float obuf[4][32][68];
  __shared__ float lls[4][32];

  int t = threadIdx.x, w = t >> 6, l = t & 63, lo = l & 31, hi = l >> 5;
  int bid = blockIdx.x;
  int b = bid & 7, qt = (bid >> 3) & 63, kh = bid >> 9;
  int q0 = qt * 32;

  const size_t laneoff = (size_t)hi * 256 + lo * 8;

  // Q B-frags: one b128 per c, coalesced
  const ushort_t* qbase = qs + (size_t)(b * 64 + qt) * 2048 + laneoff;
  bf16x8 qf[4];
#pragma unroll
  for (int c = 0; c < 4; ++c)
    qf[c] = *reinterpret_cast<const bf16x8*>(qbase + (size_t)c * 512);

  int mq = am[b * Ss + q0 + lo];
  float negq = mq ? NEG2 : 0.f;
  const float* psel = pen + ((size_t)b * 2 + (mq ? 0 : 1)) * Ss;

  float ll = 0.f;
  f32x16 o0 = {0.f, 0.f, 0.f, 0.f, 0.f, 0.f, 0.f, 0.f, 0.f, 0.f, 0.f, 0.f, 0.f, 0.f, 0.f, 0.f};
  f32x16 o1 = o0;
  const f32x16 z16 = o0;

  const int kvbeg = kh * 1024 + w * 256;
  const ushort_t* kb = km + (size_t)b * 131072 + laneoff;
  const ushort_t* vb = vm + (size_t)b * 131072 + laneoff;

  // ---- prologue: K+pen for it=0 ----
  bf16x8 kc0, kc1, kc2, kc3;
  f32x4 pc0, pc1, pc2, pc3;
  {
    const ushort_t* kfp = kb + (size_t)(kvbeg >> 5) * 2048;
    kc0 = *reinterpret_cast<const bf16x8*>(kfp);
    kc1 = *reinterpret_cast<const bf16x8*>(kfp + 512);
    kc2 = *reinterpret_cast<const bf16x8*>(kfp + 1024);
    kc3 = *reinterpret_cast<const bf16x8*>(kfp + 1536);
    pc0 = *reinterpret_cast<const f32x4*>(psel + kvbeg + 0 + hi * 4);
    pc1 = *reinterpret_cast<const f32x4*>(psel + kvbeg + 8 + hi * 4);
    pc2 = *reinterpret_cast<const f32x4*>(psel + kvbeg + 16 + hi * 4);
    pc3 = *reinterpret_cast<const f32x4*>(psel + kvbeg + 24 + hi * 4);
  }

  for (int it = 0; it < 8; ++it) {
    const int kv0 = kvbeg + it * 32;

    // ---- issue V (current it) + K/pen (it+1) loads, then pin with sched_barrier ----
    const ushort_t* vfp = vb + (size_t)(kv0 >> 4) * 1024;
    bf16x8 vf00 = *reinterpret_cast<const bf16x8*>(vfp);           // keys s16,   d 0-31
    bf16x8 vf01 = *reinterpret_cast<const bf16x8*>(vfp + 512);     // keys s16,   d 32-63
    bf16x8 vf10 = *reinterpret_cast<const bf16x8*>(vfp + 1024);    // keys s16+1, d 0-31
    bf16x8 vf11 = *reinterpret_cast<const bf16x8*>(vfp + 1536);    // keys s16+1, d 32-63

    const int kvn = (it < 7) ? kv0 + 32 : kvbeg;  // wrap: loaded, unused
    bf16x8 kn0, kn1, kn2, kn3;
    f32x4 pn0, pn1, pn2, pn3;
    {
      const ushort_t* kfp = kb + (size_t)(kvn >> 5) * 2048;
      kn0 = *reinterpret_cast<const bf16x8*>(kfp);
      kn1 = *reinterpret_cast<const bf16x8*>(kfp + 512);
      kn2 = *reinterpret_cast<const bf16x8*>(kfp + 1024);
      kn3 = *reinterpret_cast<const bf16x8*>(kfp + 1536);
      pn0 = *reinterpret_cast<const f32x4*>(psel + kvn + 0 + hi * 4);
      pn1 = *reinterpret_cast<const f32x4*>(psel + kvn + 8 + hi * 4);
      pn2 = *reinterpret_cast<const f32x4*>(psel + kvn + 16 + hi * 4);
      pn3 = *reinterpret_cast<const f32x4*>(psel + kvn + 24 + hi * 4);
    }
    __builtin_amdgcn_sched_barrier(0);  // pin load issues above all compute

    // ---- scores: D[key][q], key = (r&3)+8*(r>>2)+4*hi, q = lo ----
    f32x16 sc = mfma32(kc0, qf[0], z16);
    sc = mfma32(kc1, qf[1], sc);
    sc = mfma32(kc2, qf[2], sc);
    sc = mfma32(kc3, qf[3], sc);

    if (kv0 == q0) {  // straddle tile: per-reg causal
#pragma unroll
      for (int r = 0; r < 16; ++r) {
        int kr = (r & 3) + 8 * (r >> 2) + 4 * hi;
        float pvr = ((const float*)&pc0)[0];  // placeholder to keep shape; real below
        (void)pvr;
        sc[r] += ((r >> 2) == 0 ? pc0[r & 3] : (r >> 2) == 1 ? pc1[r & 3]
                 : (r >> 2) == 2 ? pc2[r & 3] : pc3[r & 3]) +
                 ((kr > lo) ? negq : 0.f);
      }
    } else {
      float addt = (kv0 > q0) ? negq : 0.f;
#pragma unroll
      for (int r = 0; r < 16; ++r)
        sc[r] += ((r >> 2) == 0 ? pc0[r & 3] : (r >> 2) == 1 ? pc1[r & 3]
                 : (r >> 2) == 2 ? pc2[r & 3] : pc3[r & 3]) + addt;
    }

    // ---- p = exp2(sc), row sum (fixed m = 0; cross-half reduce hoisted) ----
    float p[16], ts = 0.f;
#pragma unroll
    for (int r = 0; r < 16; ++r) {
      p[r] = __builtin_amdgcn_exp2f(sc[r]);
      ts += p[r];
    }
    ll += ts;

    // ---- P -> PV A-frags: 8 cvt_pk + 4 permlane32_swap (distinct values: safe) ----
    unsigned x0 = cvtpk(p[0], p[1]), y0 = cvtpk(p[2], p[3]);
    unsigned z0 = cvtpk(p[4], p[5]), w0 = cvtpk(p[6], p[7]);
    swap32(x0, z0);
    swap32(y0, w0);
    unsigned x1 = cvtpk(p[8], p[9]), y1 = cvtpk(p[10], p[11]);
    unsigned z1 = cvtpk(p[12], p[13]), w1 = cvtpk(p[14], p[15]);
    swap32(x1, z1);
    swap32(y1, w1);
    bf16x8 pa0 = __builtin_bit_cast(bf16x8, u32x4{x0, y0, z0, w0});
    bf16x8 pa1 = __builtin_bit_cast(bf16x8, u32x4{x1, y1, z1, w1});

    // ---- PV: D[q][d] ----
    o0 = mfma32(pa0, vf00, o0);
    o0 = mfma32(pa1, vf10, o0);
    o1 = mfma32(pa0, vf01, o1);
    o1 = mfma32(pa1, vf11, o1);

    // ---- rotate prefetched K + pen ----
    kc0 = kn0; kc1 = kn1; kc2 = kn2; kc3 = kn3;
    pc0 = pn0; pc1 = pn1; pc2 = pn2; pc3 = pn3;
  }

  ll += __shfl_xor(ll, 32);  // single cross-half reduce

  // ---- combine 4 waves' partials, emit (o, l) partial for this kh ----
#pragma unroll
  for (int r = 0; r < 16; ++r) {
    int qrow = (r & 3) + 8 * (r >> 2) + 4 * hi;
    obuf[w][qrow][lo] = o0[r];
    obuf[w][qrow][32 + lo] = o1[r];
  }
  if (hi == 0) lls[w][lo] = ll;
  __syncthreads();

  int qr = t >> 3, dg = t & 7;
  float lg = lls[0][qr] + lls[1][qr] + lls[2][qr] + lls[3][qr];
  float a8[8] = {0.f, 0.f, 0.f, 0.f, 0.f, 0.f, 0.f, 0.f};
#pragma unroll
  for (int ww = 0; ww < 4; ++ww) {
    float4 c0 = *reinterpret_cast<const float4*>(&obuf[ww][qr][dg * 8]);
    float4 c1 = *reinterpret_cast<const float4*>(&obuf[ww][qr][dg * 8 + 4]);
    a8[0] += c0.x; a8[1] += c0.y; a8[2] += c0.z; a8[3] += c0.w;
    a8[4] += c1.x; a8[5] += c1.y; a8[6] += c1.z; a8[7] += c1.w;
  }
  float* op = opart + (((size_t)kh * 8 + b) * Ss + q0 + qr) * 64 + dg * 8;
  float4 r0v = {a8[0], a8[1], a8[2], a8[3]};
  float4 r1v = {a8[4], a8[5], a8[6], a8[7]};
  *reinterpret_cast<float4*>(op) = r0v;
  *reinterpret_cast<float4*>(op + 4) = r1v;
  if (dg == 0) lpart[((size_t)kh * 8 + b) * Ss + q0 + qr] = lg;
}

// ---------------- finalize: out = (opart0 + opart1) / (l0 + l1) ----------------
__global__ __launch_bounds__(256) void k_fin(const float* __restrict__ op,
                                             const float* __restrict__ lp,
                                             float* __restrict__ out) {
  int gi = blockIdx.x * 256 + threadIdx.x;  // f32x4 chunk index, 262144 total
  int row = gi >> 4;                        // 16 chunks per 64-float row
  float lsum = lp[row] + lp[row + 16384];
  f32x4 a = reinterpret_cast<const f32x4*>(op)[gi];
  f32x4 b = reinterpret_cast<const f32x4*>(op)[gi + 262144];
  float inv = 1.f / lsum;
  f32x4 r = (a + b) * inv;
  reinterpret_cast<f32x4*>(out)[gi] = r;
}

extern "C" void kernel_launch(void* const* d_in, const int* in_sizes, int n_in,
                              void* d_out, int out_size, void* d_ws, size_t ws_size,
                              hipStream_t stream) {
  const float* hs = (const float*)d_in[0];
  const int* am = (const int*)d_in[1];
  const float* Wq = (const float*)d_in[2];
  const float* bq = (const float*)d_in[3];
  const float* Wk = (const float*)d_in[4];
  const float* bk = (const float*)d_in[5];
  const float* Wv = (const float*)d_in[6];
  const float* bv = (const float*)d_in[7];
  float* out = (float*)d_out;

  char* ws = (char*)d_ws;
  ushort_t* qsp = (ushort_t*)(ws + 0);                  // 2 MB: Q fragment-major, scaled
  ushort_t* kp = (ushort_t*)(ws + (2u << 20));          // 2 MB: K fragment-major
  ushort_t* vtp = (ushort_t*)(ws + (4u << 20));         // 2 MB: V fragment-major
  ushort_t* wtp = (ushort_t*)(ws + (6u << 20));         // 384 KB: [3][64][1024] bf16 (W^T)
  float* penp = (float*)(ws + (6u << 20) + (512u << 10));  // 128 KB: [B][2][S] f32
  float* opart = (float*)(ws + (8u << 20));             // 8 MB: [2][B][S][64] f32
  float* lpart = (float*)(ws + (16u << 20));            // 128 KB: [2][B][S] f32

  k_wtrans<<<dim3(16, 3), 256, 0, stream>>>(Wq, Wk, Wv, wtp);
  k_proj<<<dim3(256), 512, 0, stream>>>(hs, bq, bk, bv, wtp, am, qsp, kp, vtp, penp);
  k_attn<<<dim3(1024), 256, 0, stream>>>(qsp, kp, vtp, am, penp, opart, lpart);
  k_fin<<<dim3(1024), 256, 0, stream>>>(opart, lpart, out);
}

// Round 15
// 55.097 us; speedup vs baseline: 1.0697x; 1.0697x over previous
//
#include <hip/hip_runtime.h>

typedef float f32x4 __attribute__((ext_vector_type(4)));
typedef float f32x16 __attribute__((ext_vector_type(16)));
typedef unsigned int u32x4 __attribute__((ext_vector_type(4)));
typedef __bf16 bf16x8 __attribute__((ext_vector_type(8)));
typedef unsigned short ushort_t;

#define NEG2 (-144269.5f)   /* -1e5 * log2(e) */
#define SCLQ (0.18033688f)  /* 0.125 * log2(e) */

constexpr int Ss = 2048, Ee = 1024, Hh = 64;

static __device__ __forceinline__ ushort_t f2bfu(float f) {
  return __builtin_bit_cast(ushort_t, (__bf16)f);
}
static __device__ __forceinline__ f32x4 mfma16(bf16x8 a, bf16x8 b, f32x4 c) {
  return __builtin_amdgcn_mfma_f32_16x16x32_bf16(a, b, c, 0, 0, 0);
}
static __device__ __forceinline__ f32x16 mfma32(bf16x8 a, bf16x8 b, f32x16 c) {
  return __builtin_amdgcn_mfma_f32_32x32x16_bf16(a, b, c, 0, 0, 0);
}
static __device__ __forceinline__ unsigned cvtpk(float a, float b) {
  unsigned r;
  asm("v_cvt_pk_bf16_f32 %0, %1, %2" : "=v"(r) : "v"(a), "v"(b));
  return r;
}
// NOTE: only call with a,b holding DIFFERENT values (R3 bug).
static __device__ __forceinline__ void swap32(unsigned& a, unsigned& b) {
  asm("v_permlane32_swap_b32 %0, %1" : "+v"(a), "+v"(b));
}
// async global->LDS, 16B per lane; LDS dest = uniform base + lane*16 (m104)
static __device__ __forceinline__ void gload_lds16(const void* g, void* l) {
  __builtin_amdgcn_global_load_lds(
      (const __attribute__((address_space(1))) unsigned int*)g,
      (__attribute__((address_space(3))) unsigned int*)l, 16, 0, 0);
}

// ============ Fragment-major layouts (ushort element offsets) ============
// Q/K: F(b,t32,c,hi,lo,j) = ((((b*64+t32)*4+c)*2+hi)*32+lo)*8+j
// V:   G(b,s16,dt,hi,lo,j) = ((((b*128+s16)*2+dt)*2+hi)*32+lo)*8+j
// Wsw (weights, pre-swizzled for global_load_lds): step s (K-chunk of 64),
// row r = m*64+h (0..191), chunk c16 (0..7, 16B):
//   off = (s*192 + r)*64 + ((c16 ^ (r&7)) * 8)    [T2 pre-swizzle, m173]

// ---------------- weight transpose + bf16 convert -> Wsw ----------------
__global__ __launch_bounds__(256) void k_wtrans(const float* __restrict__ Wq,
                                                const float* __restrict__ Wk,
                                                const float* __restrict__ Wv,
                                                ushort_t* __restrict__ Wsw) {
  __shared__ float tile[64][65];
  const float* W = (blockIdx.y == 0) ? Wq : (blockIdx.y == 1 ? Wk : Wv);
  int kt = blockIdx.x, t = threadIdx.x;
  int r = t >> 2, cq = t & 3;
  const float* src = W + (kt * 64 + r) * Hh + cq * 16;
#pragma unroll
  for (int j = 0; j < 16; j += 4) {
    float4 v = *reinterpret_cast<const float4*>(src + j);
    tile[r][cq * 16 + j + 0] = v.x;
    tile[r][cq * 16 + j + 1] = v.y;
    tile[r][cq * 16 + j + 2] = v.z;
    tile[r][cq * 16 + j + 3] = v.w;
  }
  __syncthreads();
  int n = t >> 2, kq = t & 3;
  int rr = blockIdx.y * 64 + n;  // W row 0..191
  ushort_t ob[16];
#pragma unroll
  for (int j = 0; j < 16; ++j) ob[j] = f2bfu(tile[kq * 16 + j][n]);
#pragma unroll
  for (int j = 0; j < 2; ++j) {
    int c16 = 2 * kq + j;
    size_t off = ((size_t)(kt * 192 + rr)) * 64 + (size_t)(((c16 ^ (rr & 7))) * 8);
    *reinterpret_cast<uint4*>(Wsw + off) = reinterpret_cast<uint4*>(ob)[j];
  }
}

// ---------------- fused QKV projection v2: async-W + single-barrier pipeline ----
// 256 blocks x 512 thr (8 waves). Tile 64 rows x 192 cols, 16 K-steps of 64.
// W staged via global_load_lds width=16 from pre-swizzled Wsw (linear LDS dest
// == swizzled layout); reads use slot = g^(r&7) — same bank profile as the old
// padded layout, but no VGPR round-trip and async issue a full step early.
// A (hs) reg-staged (needs f32->bf16 cvt), issued 2 steps early, pinned by
// sched_barrier(0). Single barrier per step (R11 pattern):
//   { bar; WRITEA(next); GLW(next); LOADA(next+2); COMPUTE(cur) }.
// Epilogue scatters into fragment-major q/k/v layouts.
__global__ __launch_bounds__(512, 4) void k_proj(const float* __restrict__ hs,
                                                 const float* __restrict__ bq,
                                                 const float* __restrict__ bk,
                                                 const float* __restrict__ bv,
                                                 const ushort_t* __restrict__ Wsw,
                                                 const int* __restrict__ am,
                                                 ushort_t* __restrict__ qf_,
                                                 ushort_t* __restrict__ kf_,
                                                 ushort_t* __restrict__ vf_,
                                                 float* __restrict__ pen) {
  __shared__ __align__(16) ushort_t bufA[2][64][72];      // 18 KB (padded, reg-staged)
  __shared__ __align__(16) ushort_t bufW[2][192 * 64];    // 48 KB (swizzled via Wsw)

  int t = threadIdx.x, w = t >> 6, l = t & 63, g = l >> 4, c = l & 15;
  int wm = w >> 1, wn = w & 1;
  int row0 = blockIdx.x * 64;

  int ar = t >> 3, ach = t & 7;
  const float* agp = hs + (size_t)(row0 + ar) * Ee + ach * 8;

  f32x4 acc[6];
#pragma unroll
  for (int nt = 0; nt < 6; ++nt) acc[nt] = f32x4{0.f, 0.f, 0.f, 0.f};

  float4 aR0, aR1;

  auto LOADA = [&](int kk) {
    aR0 = *reinterpret_cast<const float4*>(agp + kk);
    aR1 = *reinterpret_cast<const float4*>(agp + kk + 4);
  };
  auto WRITEA = [&](int buf) {
    bf16x8 av;
    av[0] = (__bf16)aR0.x; av[1] = (__bf16)aR0.y; av[2] = (__bf16)aR0.z; av[3] = (__bf16)aR0.w;
    av[4] = (__bf16)aR1.x; av[5] = (__bf16)aR1.y; av[6] = (__bf16)aR1.z; av[7] = (__bf16)aR1.w;
    *reinterpret_cast<bf16x8*>(&bufA[buf][ar][ach * 8]) = av;
  };
  auto GLW = [&](int buf, int s) {
    const ushort_t* base = Wsw + (size_t)s * 12288;
#pragma unroll
    for (int j = 0; j < 3; ++j) {
      int seg = j * 8 + w;                          // 0..23, wave-uniform
      const ushort_t* gp = base + seg * 512 + l * 8;  // per-lane 16B
      gload_lds16(gp, &bufW[buf][seg * 512]);
    }
  };
  auto COMPUTE = [&](int buf) {
    const ushort_t* Ab = &bufA[buf][wm * 16 + c][0];
    bf16x8 af0 = *reinterpret_cast<const bf16x8*>(Ab + g * 8);
    bf16x8 af1 = *reinterpret_cast<const bf16x8*>(Ab + 32 + g * 8);
#pragma unroll
    for (int nt = 0; nt < 6; ++nt) {
      int r = wn * 96 + nt * 16 + c;
      int slot = g ^ (r & 7);
      const ushort_t* Wb = &bufW[buf][r * 64];
      bf16x8 b0 = *reinterpret_cast<const bf16x8*>(Wb + slot * 8);
      bf16x8 b1 = *reinterpret_cast<const bf16x8*>(Wb + (slot ^ 4) * 8);
      acc[nt] = mfma16(af0, b0, acc[nt]);
      acc[nt] = mfma16(af1, b1, acc[nt]);
    }
  };

  // prologue
  LOADA(0);
  WRITEA(0);       // vmcnt-waits the A loads
  GLW(0, 0);
  LOADA(64);       // A regs for step 1
  __builtin_amdgcn_sched_barrier(0);

  int cur = 0;
  for (int s = 0; s < 16; ++s) {
    __syncthreads();  // drains GLW/ds_writes for buf cur; releases buf cur^1
    if (s < 15) {
      WRITEA(cur ^ 1);       // A for step s+1 (loaded 1-2 steps ago)
      GLW(cur ^ 1, s + 1);   // async W for step s+1: full COMPUTE of cover
    }
    if (s < 14) {
      LOADA((s + 2) * 64);
      __builtin_amdgcn_sched_barrier(0);  // pin A issue early (R5 lesson)
    }
    COMPUTE(cur);
    cur ^= 1;
  }

  // epilogue: scatter into fragment-major layouts
#pragma unroll
  for (int nt = 0; nt < 6; ++nt) {
    int T = wn * 6 + nt;
    int m = T >> 2;
    int h = (T & 3) * 16 + c;
    const float* bias = (m == 0) ? bq : ((m == 1) ? bk : bv);
    float bb = bias[h];
    int cc = h >> 4, hh = (h >> 3) & 1, jj = h & 7;      // Q/K frag coords
    int dt = h >> 5, dl = h & 31;                         // V frag coords
#pragma unroll
    for (int i = 0; i < 4; ++i) {
      int row = row0 + wm * 16 + g * 4 + i;
      float val = acc[nt][i] + bb;
      int bi = row >> 11, rl = row & 2047;
      if (m == 0) {
        size_t a = ((((size_t)(bi * 64 + (rl >> 5)) * 4 + cc) * 2 + hh) * 32 + (rl & 31)) * 8 + jj;
        qf_[a] = f2bfu(val * SCLQ);
      } else if (m == 1) {
        size_t a = ((((size_t)(bi * 64 + (rl >> 5)) * 4 + cc) * 2 + hh) * 32 + (rl & 31)) * 8 + jj;
        kf_[a] = f2bfu(val);
      } else {
        int s16 = rl >> 4, vh = (rl >> 3) & 1, vj = rl & 7;
        size_t a = ((((size_t)(bi * 128 + s16) * 2 + dt) * 2 + vh) * 32 + dl) * 8 + vj;
        vf_[a] = f2bfu(val);
      }
    }
  }

  if (t < 64) {
    int grow = row0 + t;
    int bi = grow >> 11, s2 = grow & 2047;
    int mv = am[grow];
    pen[((size_t)bi * 2 + 0) * Ss + s2] = mv ? 0.f : NEG2;
    pen[((size_t)bi * 2 + 1) * Ss + s2] = mv ? NEG2 : 0.f;
  }
}

// ---------------- fused masked flash attention (R13, proven): frag-major ----
// grid 1024: b = bid&7 (batch-per-XCD), qt = (bid>>3)&63, kh = bid>>9 (k-split).
// 256 thr / 4 waves; wave w owns keys [kh*1024 + w*256, +256). Every K/V/Q
// fragment load is ONE coalesced b128 (L2-resident); no LDS staging, no loop
// barriers; launch_bounds(256,3) (cap ~170 >= ~130 live; (256,4) spills — R12).
// Fixed m=0 softmax -> k-split partials are plain sums; k_fin combines.
__global__ __launch_bounds__(256, 3) void k_attn(const ushort_t* __restrict__ qs,
                                                 const ushort_t* __restrict__ km,
                                                 const ushort_t* __restrict__ vm,
                                                 const int* __restrict__ am,
                                                 const float* __restrict__ pen,
                                                 float* __restrict__ opart,
                                                 float* __restrict__ lpart) {
  __shared__ float obuf[4][32][68];
  __shared__ float lls[4][32];

  int t = threadIdx.x, w = t >> 6, l = t & 63, lo = l & 31, hi = l >> 5;
  int bid = blockIdx.x;
  int b = bid & 7, qt = (bid >> 3) & 63, kh = bid >> 9;
  int q0 = qt * 32;

  const size_t laneoff = (size_t)hi * 256 + lo * 8;

  const ushort_t* qbase = qs + (size_t)(b * 64 + qt) * 2048 + laneoff;
  bf16x8 qf[4];
#pragma unroll
  for (int c = 0; c < 4; ++c)
    qf[c] = *reinterpret_cast<const bf16x8*>(qbase + (size_t)c * 512);

  int mq = am[b * Ss + q0 + lo];
  float negq = mq ? NEG2 : 0.f;
  const float* psel = pen + ((size_t)b * 2 + (mq ? 0 : 1)) * Ss;

  float ll = 0.f;
  f32x16 o0 = {0.f, 0.f, 0.f, 0.f, 0.f, 0.f, 0.f, 0.f, 0.f, 0.f, 0.f, 0.f, 0.f, 0.f, 0.f, 0.f};
  f32x16 o1 = o0;
  const f32x16 z16 = o0;

  const int kvbeg = kh * 1024 + w * 256;
  const ushort_t* kb = km + (size_t)b * 131072 + laneoff;
  const ushort_t* vb = vm + (size_t)b * 131072 + laneoff;

  for (int it = 0; it < 8; ++it) {
    const int kv0 = kvbeg + it * 32;
    const int kt32 = kv0 >> 5, s16 = kv0 >> 4;

    const ushort_t* kfp = kb + (size_t)kt32 * 2048;
    bf16x8 kf0 = *reinterpret_cast<const bf16x8*>(kfp);
    bf16x8 kf1 = *reinterpret_cast<const bf16x8*>(kfp + 512);
    bf16x8 kf2 = *reinterpret_cast<const bf16x8*>(kfp + 1024);
    bf16x8 kf3 = *reinterpret_cast<const bf16x8*>(kfp + 1536);
    const ushort_t* vfp = vb + (size_t)s16 * 1024;
    bf16x8 vf00 = *reinterpret_cast<const bf16x8*>(vfp);
    bf16x8 vf01 = *reinterpret_cast<const bf16x8*>(vfp + 512);
    bf16x8 vf10 = *reinterpret_cast<const bf16x8*>(vfp + 1024);
    bf16x8 vf11 = *reinterpret_cast<const bf16x8*>(vfp + 1536);

    f32x4 pv[4];
#pragma unroll
    for (int j = 0; j < 4; ++j)
      pv[j] = *reinterpret_cast<const f32x4*>(psel + kv0 + j * 8 + hi * 4);

    f32x16 sc = mfma32(kf0, qf[0], z16);
    sc = mfma32(kf1, qf[1], sc);
    sc = mfma32(kf2, qf[2], sc);
    sc = mfma32(kf3, qf[3], sc);

    if (kv0 == q0) {
#pragma unroll
      for (int r = 0; r < 16; ++r) {
        int kr = (r & 3) + 8 * (r >> 2) + 4 * hi;
        sc[r] += pv[r >> 2][r & 3] + ((kr > lo) ? negq : 0.f);
      }
    } else {
      float addt = (kv0 > q0) ? negq : 0.f;
#pragma unroll
      for (int r = 0; r < 16; ++r) sc[r] += pv[r >> 2][r & 3] + addt;
    }

    float p[16], ts = 0.f;
#pragma unroll
    for (int r = 0; r < 16; ++r) {
      p[r] = __builtin_amdgcn_exp2f(sc[r]);
      ts += p[r];
    }
    ll += ts;

    unsigned x0 = cvtpk(p[0], p[1]), y0 = cvtpk(p[2], p[3]);
    unsigned z0 = cvtpk(p[4], p[5]), w0 = cvtpk(p[6], p[7]);
    swap32(x0, z0);
    swap32(y0, w0);
    unsigned x1 = cvtpk(p[8], p[9]), y1 = cvtpk(p[10], p[11]);
    unsigned z1 = cvtpk(p[12], p[13]), w1 = cvtpk(p[14], p[15]);
    swap32(x1, z1);
    swap32(y1, w1);
    bf16x8 pa0 = __builtin_bit_cast(bf16x8, u32x4{x0, y0, z0, w0});
    bf16x8 pa1 = __builtin_bit_cast(bf16x8, u32x4{x1, y1, z1, w1});

    o0 = mfma32(pa0, vf00, o0);
    o0 = mfma32(pa1, vf10, o0);
    o1 = mfma32(pa0, vf01, o1);
    o1 = mfma32(pa1, vf11, o1);
  }

  ll += __shfl_xor(ll, 32);

#pragma unroll
  for (int r = 0; r < 16; ++r) {
    int qrow = (r & 3) + 8 * (r >> 2) + 4 * hi;
    obuf[w][qrow][lo] = o0[r];
    obuf[w][qrow][32 + lo] = o1[r];
  }
  if (hi == 0) lls[w][lo] = ll;
  __syncthreads();

  int qr = t >> 3, dg = t & 7;
  float lg = lls[0][qr] + lls[1][qr] + lls[2][qr] + lls[3][qr];
  float a8[8] = {0.f, 0.f, 0.f, 0.f, 0.f, 0.f, 0.f, 0.f};
#pragma unroll
  for (int ww = 0; ww < 4; ++ww) {
    float4 c0 = *reinterpret_cast<const float4*>(&obuf[ww][qr][dg * 8]);
    float4 c1 = *reinterpret_cast<const float4*>(&obuf[ww][qr][dg * 8 + 4]);
    a8[0] += c0.x; a8[1] += c0.y; a8[2] += c0.z; a8[3] += c0.w;
    a8[4] += c1.x; a8[5] += c1.y; a8[6] += c1.z; a8[7] += c1.w;
  }
  float* op = opart + (((size_t)kh * 8 + b) * Ss + q0 + qr) * 64 + dg * 8;
  float4 r0v = {a8[0], a8[1], a8[2], a8[3]};
  float4 r1v = {a8[4], a8[5], a8[6], a8[7]};
  *reinterpret_cast<float4*>(op) = r0v;
  *reinterpret_cast<float4*>(op + 4) = r1v;
  if (dg == 0) lpart[((size_t)kh * 8 + b) * Ss + q0 + qr] = lg;
}

// ---------------- finalize: out = (opart0 + opart1) / (l0 + l1) ----------------
__global__ __launch_bounds__(256) void k_fin(const float* __restrict__ op,
                                             const float* __restrict__ lp,
                                             float* __restrict__ out) {
  int gi = blockIdx.x * 256 + threadIdx.x;
  int row = gi >> 4;
  float lsum = lp[row] + lp[row + 16384];
  f32x4 a = reinterpret_cast<const f32x4*>(op)[gi];
  f32x4 b = reinterpret_cast<const f32x4*>(op)[gi + 262144];
  float inv = 1.f / lsum;
  f32x4 r = (a + b) * inv;
  reinterpret_cast<f32x4*>(out)[gi] = r;
}

extern "C" void kernel_launch(void* const* d_in, const int* in_sizes, int n_in,
                              void* d_out, int out_size, void* d_ws, size_t ws_size,
                              hipStream_t stream) {
  const float* hs = (const float*)d_in[0];
  const int* am = (const int*)d_in[1];
  const float* Wq = (const float*)d_in[2];
  const float* bq = (const float*)d_in[3];
  const float* Wk = (const float*)d_in[4];
  const float* bk = (const float*)d_in[5];
  const float* Wv = (const float*)d_in[6];
  const float* bv = (const float*)d_in[7];
  float* out = (float*)d_out;

  char* ws = (char*)d_ws;
  ushort_t* qsp = (ushort_t*)(ws + 0);                  // 2 MB: Q fragment-major, scaled
  ushort_t* kp = (ushort_t*)(ws + (2u << 20));          // 2 MB: K fragment-major
  ushort_t* vtp = (ushort_t*)(ws + (4u << 20));         // 2 MB: V fragment-major
  ushort_t* wtp = (ushort_t*)(ws + (6u << 20));         // 384 KB: Wsw pre-swizzled
  float* penp = (float*)(ws + (6u << 20) + (512u << 10));  // 128 KB: [B][2][S] f32
  float* opart = (float*)(ws + (8u << 20));             // 8 MB: [2][B][S][64] f32
  float* lpart = (float*)(ws + (16u << 20));            // 128 KB: [2][B][S] f32

  k_wtrans<<<dim3(16, 3), 256, 0, stream>>>(Wq, Wk, Wv, wtp);
  k_proj<<<dim3(256), 512, 0, stream>>>(hs, bq, bk, bv, wtp, am, qsp, kp, vtp, penp);
  k_attn<<<dim3(1024), 256, 0, stream>>>(qsp, kp, vtp, am, penp, opart, lpart);
  k_fin<<<dim3(1024), 256, 0, stream>>>(opart, lpart, out);
}